// Round 1
// baseline (54.170 us; speedup 1.0000x reference)
//
#include <hip/hip_runtime.h>

#define NPTS 128
#define FAR_DELTA 1e10f
#define EPS_T 1e-10f

__global__ __launch_bounds__(256) void volsdf_render_kernel(
    const float* __restrict__ distance,
    const float* __restrict__ color,
    const float* __restrict__ slen,
    float* __restrict__ out_color,
    float* __restrict__ geometry,
    int npairs)
{
    // 256 threads = 2 rays per block, 128 threads (2 waves) per ray.
    const int half  = threadIdx.x >> 7;        // 0/1: which ray of the pair
    const int p     = threadIdx.x & 127;       // point index within ray
    const int lane  = threadIdx.x & 63;        // lane within wave
    const int whalf = (threadIdx.x >> 6) & 1;  // wave index within the half (0/1)

    __shared__ float s_sl[2][NPTS];
    __shared__ float s_wave[2];
    __shared__ float s_red[2][2][3];

    for (int pair = blockIdx.x; pair < npairs; pair += gridDim.x) {
        const int r = pair * 2 + half;
        const size_t base = (size_t)r * NPTS;

        // Coalesced per-ray loads
        float d  = distance[base + p];
        float sl = slen[base + p];
        const float* cp = color + base * 3 + (size_t)p * 3;
        float c0 = cp[0], c1 = cp[1], c2 = cp[2];

        s_sl[half][p] = sl;
        __syncthreads();
        float delta = (p < NPTS - 1) ? (s_sl[half][p + 1] - sl) : FAR_DELTA;

        // density = ALPHA * sigmoid(-d/BETA) = 10 / (1 + exp(20 d))
        float density = 10.0f / (1.0f + __expf(20.0f * d));
        // e = exp(-density*delta);  alpha = 1-e;  (1-alpha+eps) = e+eps (no cancellation)
        float e = __expf(-density * delta);
        float alpha = 1.0f - e;

        // Block-half-wide inclusive product scan of t = e + eps
        float prod = e + EPS_T;
        #pragma unroll
        for (int off = 1; off < 64; off <<= 1) {
            float up = __shfl_up(prod, off, 64);
            if (lane >= off) prod *= up;
        }
        if (p == 63) s_wave[half] = prod;      // wave-0-of-half total
        __syncthreads();
        float w0 = s_wave[half];
        if (whalf == 1) prod *= w0;            // now prod = inclusive scan over 128

        // Exclusive: trans[p] = inclusive[p-1], trans[0] = 1
        float up1 = __shfl_up(prod, 1, 64);
        float trans = (p == 0) ? 1.0f : ((p == 64) ? w0 : up1);

        float w = trans * alpha;

        // Reduce w * color over the 128 points (per-wave tree, then LDS combine)
        float s0 = w * c0, s1 = w * c1, s2 = w * c2;
        #pragma unroll
        for (int off = 32; off > 0; off >>= 1) {
            s0 += __shfl_down(s0, off, 64);
            s1 += __shfl_down(s1, off, 64);
            s2 += __shfl_down(s2, off, 64);
        }
        if (lane == 0) {
            s_red[half][whalf][0] = s0;
            s_red[half][whalf][1] = s1;
            s_red[half][whalf][2] = s2;
        }
        __syncthreads();
        if (p < 3)
            out_color[(size_t)r * 3 + p] = s_red[half][0][p] + s_red[half][1][p];

        // geometry = zeros: 384 floats/ray = 96 float4 stores (16B-aligned)
        if (p < 96)
            reinterpret_cast<float4*>(geometry + base * 3)[p] =
                make_float4(0.f, 0.f, 0.f, 0.f);
        // No trailing barrier needed: next iteration's first write to s_sl is
        // separated from this iteration's last read by >=2 barriers.
    }
}

extern "C" void kernel_launch(void* const* d_in, const int* in_sizes, int n_in,
                              void* d_out, int out_size, void* d_ws, size_t ws_size,
                              hipStream_t stream) {
    const float* distance = (const float*)d_in[0];
    const float* color    = (const float*)d_in[1];
    const float* slen     = (const float*)d_in[2];

    const int R = in_sizes[0] / NPTS;   // 65536
    float* out_color = (float*)d_out;
    float* geometry  = out_color + (size_t)R * 3;

    const int npairs = R / 2;           // R is even (65536)
    int grid = npairs < 2048 ? npairs : 2048;  // 8 blocks/CU full residency
    hipLaunchKernelGGL(volsdf_render_kernel, dim3(grid), dim3(256), 0, stream,
                       distance, color, slen, out_color, geometry, npairs);
}

// Round 2
// 36.366 us; speedup vs baseline: 1.4896x; 1.4896x over previous
//
#include <hip/hip_runtime.h>

#define NPTS 128
#define FAR_DELTA 1e10f
#define EPS_T 1e-10f
#define TRANS_CUTOFF 1e-4f   // skipping color when trans < this adds <= 1e-4 abs error

__global__ __launch_bounds__(256) void volsdf_render_kernel(
    const float* __restrict__ distance,
    const float* __restrict__ color,
    const float* __restrict__ slen,
    float* __restrict__ out_color,
    float* __restrict__ geometry,
    int nrays)
{
    // One wave (64 lanes) per ray; 2 points per lane. No LDS, no barriers.
    const int wave = threadIdx.x >> 6;   // 0..3 within block
    const int lane = threadIdx.x & 63;

    for (int r = blockIdx.x * 4 + wave; r < nrays; r += gridDim.x * 4) {
        const size_t base = (size_t)r * NPTS;

        // Points p0 = 2*lane, p1 = 2*lane+1. float2 loads, 8B-aligned, coalesced.
        float2 dd = *reinterpret_cast<const float2*>(distance + base + 2 * lane);
        float2 ss = *reinterpret_cast<const float2*>(slen + base + 2 * lane);

        // deltas: next sample depth minus current; last point gets FAR_DELTA
        float sl_next = __shfl_down(ss.x, 1, 64);          // lane+1's first depth
        float delta0 = ss.y - ss.x;
        float delta1 = (lane == 63) ? FAR_DELTA : (sl_next - ss.y);

        // density = 10 * sigmoid(-d/0.05) = 10 / (1 + exp(20 d))
        float dens0 = 10.0f / (1.0f + __expf(20.0f * dd.x));
        float dens1 = 10.0f / (1.0f + __expf(20.0f * dd.y));
        // e = exp(-density*delta); (1 - alpha + eps) = e + eps (no cancellation)
        float e0 = __expf(-dens0 * delta0);
        float e1 = __expf(-dens1 * delta1);
        float t0 = e0 + EPS_T, t1 = e1 + EPS_T;

        // In-wave inclusive product scan of per-lane pair products
        float local = t0 * t1;
        float incl = local;
        #pragma unroll
        for (int off = 1; off < 64; off <<= 1) {
            float up = __shfl_up(incl, off, 64);
            if (lane >= off) incl *= up;
        }
        // Exclusive prefix at point p0; p1's prefix = excl * t0
        float excl = __shfl_up(incl, 1, 64);
        if (lane == 0) excl = 1.0f;

        float w0 = excl * (1.0f - e0);
        float w1 = excl * t0 * (1.0f - e1);

        // Gated color load: beyond trans < cutoff, remaining weight sum <= cutoff
        float s0 = 0.f, s1 = 0.f, s2 = 0.f;
        if (excl >= TRANS_CUTOFF) {
            const float* cp = color + (base + 2 * (size_t)lane) * 3;  // 8B-aligned
            float2 a = *reinterpret_cast<const float2*>(cp);      // c0.r c0.g
            float2 b = *reinterpret_cast<const float2*>(cp + 2);  // c0.b c1.r
            float2 c = *reinterpret_cast<const float2*>(cp + 4);  // c1.g c1.b
            s0 = w0 * a.x + w1 * b.y;
            s1 = w0 * a.y + w1 * c.x;
            s2 = w0 * b.x + w1 * c.y;
        }

        // Wave tree-reduce the 3 channels
        #pragma unroll
        for (int off = 32; off > 0; off >>= 1) {
            s0 += __shfl_down(s0, off, 64);
            s1 += __shfl_down(s1, off, 64);
            s2 += __shfl_down(s2, off, 64);
        }
        if (lane == 0) {
            float* op = out_color + (size_t)r * 3;
            op[0] = s0; op[1] = s1; op[2] = s2;
        }

        // geometry = zeros: 384 floats/ray = 96 float4 stores (base*3 is 1536B-aligned)
        float4* g4 = reinterpret_cast<float4*>(geometry + base * 3);
        const float4 z = make_float4(0.f, 0.f, 0.f, 0.f);
        g4[lane] = z;
        if (lane < 32) g4[64 + lane] = z;
    }
}

extern "C" void kernel_launch(void* const* d_in, const int* in_sizes, int n_in,
                              void* d_out, int out_size, void* d_ws, size_t ws_size,
                              hipStream_t stream) {
    const float* distance = (const float*)d_in[0];
    const float* color    = (const float*)d_in[1];
    const float* slen     = (const float*)d_in[2];

    const int R = in_sizes[0] / NPTS;   // 65536
    float* out_color = (float*)d_out;
    float* geometry  = out_color + (size_t)R * 3;

    int grid = 2048;  // 8 blocks/CU (256 thr, 20 VGPR) = full 32-wave residency
    hipLaunchKernelGGL(volsdf_render_kernel, dim3(grid), dim3(256), 0, stream,
                       distance, color, slen, out_color, geometry, R);
}

// Round 4
// 33.047 us; speedup vs baseline: 1.6392x; 1.1004x over previous
//
#include <hip/hip_runtime.h>

#define NPTS 128
#define FAR_DELTA 1e10f
#define EPS_T 1e-10f
#define TRANS_CUTOFF 1e-4f   // skipping color when trans < this adds <= 1e-4 abs error

typedef float floatx4 __attribute__((ext_vector_type(4)));  // native vec for nontemporal builtin

// --- DPP cross-lane helpers (all VALU, no DS pipe) ---------------------------
// ctrl encodings (gfx9/CDNA): row_shr:N = 0x110+N, wave_shl1 = 0x130,
// wave_shr1 = 0x138, row_bcast15 = 0x142, row_bcast31 = 0x143.
// update_dpp(old, src, ...bound_ctrl=false): invalid/masked lanes return `old`
// -> supply the operation identity there.

template <int CTRL, int RMASK>
__device__ __forceinline__ float dpp_mul_step(float x) {
    int y = __builtin_amdgcn_update_dpp(__float_as_int(1.0f), __float_as_int(x),
                                        CTRL, RMASK, 0xf, false);
    return x * __int_as_float(y);
}

template <int CTRL, int RMASK>
__device__ __forceinline__ float dpp_add_step(float x) {
    int y = __builtin_amdgcn_update_dpp(0, __float_as_int(x),
                                        CTRL, RMASK, 0xf, false);
    return x + __int_as_float(y);
}

// Inclusive product scan over 64 lanes (LLVM AtomicOptimizer wave64 sequence)
__device__ __forceinline__ float wave_incl_prod_scan(float x) {
    x = dpp_mul_step<0x111, 0xf>(x);  // row_shr:1
    x = dpp_mul_step<0x112, 0xf>(x);  // row_shr:2
    x = dpp_mul_step<0x114, 0xf>(x);  // row_shr:4
    x = dpp_mul_step<0x118, 0xf>(x);  // row_shr:8
    x = dpp_mul_step<0x142, 0xa>(x);  // row_bcast:15 -> rows 1,3
    x = dpp_mul_step<0x143, 0xc>(x);  // row_bcast:31 -> rows 2,3
    return x;
}

// Sum over 64 lanes; full total lands in lane 63
__device__ __forceinline__ float wave_sum_to_lane63(float s) {
    s = dpp_add_step<0x111, 0xf>(s);
    s = dpp_add_step<0x112, 0xf>(s);
    s = dpp_add_step<0x114, 0xf>(s);
    s = dpp_add_step<0x118, 0xf>(s);
    s = dpp_add_step<0x142, 0xa>(s);
    s = dpp_add_step<0x143, 0xc>(s);
    return s;
}

__global__ __launch_bounds__(256) void volsdf_render_kernel(
    const float* __restrict__ distance,
    const float* __restrict__ color,
    const float* __restrict__ slen,
    float* __restrict__ out_color,
    float* __restrict__ geometry,
    int nrays)
{
    // One wave (64 lanes) per ray; 2 points per lane. No LDS, no barriers, no DS ops.
    const int wave = threadIdx.x >> 6;   // 0..3 within block
    const int lane = threadIdx.x & 63;

    for (int r = blockIdx.x * 4 + wave; r < nrays; r += gridDim.x * 4) {
        const size_t base = (size_t)r * NPTS;

        // Points p0 = 2*lane, p1 = 2*lane+1. float2 loads, 8B-aligned, coalesced.
        float2 dd = *reinterpret_cast<const float2*>(distance + base + 2 * lane);
        float2 ss = *reinterpret_cast<const float2*>(slen + base + 2 * lane);

        // deltas: lane+1's first depth via wave_shl:1 (lane 63 unused -> FAR_DELTA)
        int sn = __builtin_amdgcn_update_dpp(0, __float_as_int(ss.x),
                                             0x130, 0xf, 0xf, false);
        float sl_next = __int_as_float(sn);
        float delta0 = ss.y - ss.x;
        float delta1 = (lane == 63) ? FAR_DELTA : (sl_next - ss.y);

        // density = 10 * sigmoid(-d/0.05) = 10 / (1 + exp(20 d))
        float dens0 = 10.0f / (1.0f + __expf(20.0f * dd.x));
        float dens1 = 10.0f / (1.0f + __expf(20.0f * dd.y));
        // e = exp(-density*delta); (1 - alpha + eps) = e + eps (no cancellation)
        float e0 = __expf(-dens0 * delta0);
        float e1 = __expf(-dens1 * delta1);
        float t0 = e0 + EPS_T, t1 = e1 + EPS_T;

        // Inclusive product scan of per-lane pair products, then exclusive shift
        float incl = wave_incl_prod_scan(t0 * t1);
        int ei = __builtin_amdgcn_update_dpp(__float_as_int(1.0f),
                                             __float_as_int(incl),
                                             0x138, 0xf, 0xf, false); // wave_shr:1
        float excl = __int_as_float(ei);   // lane 0 -> 1.0 via `old`

        float w0 = excl * (1.0f - e0);
        float w1 = excl * t0 * (1.0f - e1);

        // Gated color load: beyond trans < cutoff, remaining weight sum <= cutoff
        float s0 = 0.f, s1 = 0.f, s2 = 0.f;
        if (excl >= TRANS_CUTOFF) {
            const float* cp = color + (base + 2 * (size_t)lane) * 3;  // 8B-aligned
            float2 a = *reinterpret_cast<const float2*>(cp);      // c0.r c0.g
            float2 b = *reinterpret_cast<const float2*>(cp + 2);  // c0.b c1.r
            float2 c = *reinterpret_cast<const float2*>(cp + 4);  // c1.g c1.b
            s0 = w0 * a.x + w1 * b.y;
            s1 = w0 * a.y + w1 * c.x;
            s2 = w0 * b.x + w1 * c.y;
        }

        // 3-channel wave sum; totals land in lane 63
        s0 = wave_sum_to_lane63(s0);
        s1 = wave_sum_to_lane63(s1);
        s2 = wave_sum_to_lane63(s2);
        if (lane == 63) {
            float* op = out_color + (size_t)r * 3;
            op[0] = s0; op[1] = s1; op[2] = s2;
        }

        // geometry = zeros: 96 float4-wide nontemporal stores (bypass caches so
        // the inputs stay Infinity-Cache-resident across replays)
        floatx4* g4 = reinterpret_cast<floatx4*>(geometry + base * 3);
        const floatx4 z = {0.f, 0.f, 0.f, 0.f};
        __builtin_nontemporal_store(z, g4 + lane);
        if (lane < 32) __builtin_nontemporal_store(z, g4 + 64 + lane);
    }
}

extern "C" void kernel_launch(void* const* d_in, const int* in_sizes, int n_in,
                              void* d_out, int out_size, void* d_ws, size_t ws_size,
                              hipStream_t stream) {
    const float* distance = (const float*)d_in[0];
    const float* color    = (const float*)d_in[1];
    const float* slen     = (const float*)d_in[2];

    const int R = in_sizes[0] / NPTS;   // 65536
    float* out_color = (float*)d_out;
    float* geometry  = out_color + (size_t)R * 3;

    int grid = 2048;  // 8 blocks/CU (256 thr, ~20 VGPR) = full 32-wave residency
    hipLaunchKernelGGL(volsdf_render_kernel, dim3(grid), dim3(256), 0, stream,
                       distance, color, slen, out_color, geometry, R);
}